// Round 1
// baseline (535.843 us; speedup 1.0000x reference)
//
#include <hip/hip_runtime.h>
#include <hip/hip_bf16.h>
#include <stdint.h>

// LSTM cell: gates = [X|h0](16384x2048) @ Bt^T(2048x4096), fused epilogue.
// bf16 MFMA 16x16x32. This version: 256x256 tile, 8 waves, BK=32,
// 4-deep LDS pipeline with counted vmcnt(4) (T3+T4), setprio around MFMA
// clusters (T5), raw s_barrier (no vmcnt drain), XCD-swizzled block ids (T1).
// Gate-interleaved p-space so acc[mi][0..3] = gates i,f,g,o of ONE output
// column in the SAME lane -> epilogue is pure register math.

typedef __bf16 bf16x8 __attribute__((ext_vector_type(8)));
typedef float f32x4 __attribute__((ext_vector_type(4)));

#define B_ROWS 16384
#define KDIM 2048
#define DH 1024
#define HC_ELEMS 16777216ull  // 16384*1024
#define NT 64                 // K-tiles of BK=32

__device__ __forceinline__ unsigned short f2bf(float f) {
  unsigned u = __float_as_uint(f);
  u = (u + 0x7fffu + ((u >> 16) & 1u)) >> 16;  // RNE
  return (unsigned short)u;
}

__device__ __forceinline__ float fsig(float x) {
  return __builtin_amdgcn_rcpf(1.0f + __expf(-x));
}
__device__ __forceinline__ float ftanh_(float x) {
  return 2.0f * __builtin_amdgcn_rcpf(1.0f + __expf(-2.0f * x)) - 1.0f;
}

// A[m][k] = k<1024 ? X[m][k] : h0[m][k-1024], cast to bf16. 8 elems/thread.
__global__ void cast_concat_A(const float* __restrict__ X, const float* __restrict__ h0,
                              unsigned short* __restrict__ A) {
  size_t t = (size_t)blockIdx.x * 256 + threadIdx.x;
  size_t idx = t * 8;
  int m = (int)(idx >> 11);
  int k = (int)(idx & 2047);
  const float* src = (k < 1024) ? (X + (size_t)m * 1024 + k)
                                : (h0 + (size_t)m * 1024 + (k - 1024));
  float4 a = ((const float4*)src)[0];
  float4 b = ((const float4*)src)[1];
  union { unsigned short u[8]; uint4 v; } pk;
  pk.u[0] = f2bf(a.x); pk.u[1] = f2bf(a.y); pk.u[2] = f2bf(a.z); pk.u[3] = f2bf(a.w);
  pk.u[4] = f2bf(b.x); pk.u[5] = f2bf(b.y); pk.u[6] = f2bf(b.z); pk.u[7] = f2bf(b.w);
  *(uint4*)(A + idx) = pk.v;
}

// Bt[n][1024+k'] = W[n][k'] (contiguous copy+cast). 8 elems/thread.
__global__ void cast_W(const float* __restrict__ W, unsigned short* __restrict__ Bt) {
  size_t t = (size_t)blockIdx.x * 256 + threadIdx.x;
  size_t idx = t * 8;  // over 4096*1024
  int n = (int)(idx >> 10);
  int k = (int)(idx & 1023);
  const float* src = W + (size_t)n * 1024 + k;
  float4 a = ((const float4*)src)[0];
  float4 b = ((const float4*)src)[1];
  union { unsigned short u[8]; uint4 v; } pk;
  pk.u[0] = f2bf(a.x); pk.u[1] = f2bf(a.y); pk.u[2] = f2bf(a.z); pk.u[3] = f2bf(a.w);
  pk.u[4] = f2bf(b.x); pk.u[5] = f2bf(b.y); pk.u[6] = f2bf(b.z); pk.u[7] = f2bf(b.w);
  *(uint4*)(Bt + (size_t)n * 2048 + 1024 + k) = pk.v;
}

// Bt[n][k] = U[k][n] for k<1024. 32x32 LDS tile transpose, fp32->bf16.
__global__ void transpose_U(const float* __restrict__ U, unsigned short* __restrict__ Bt) {
  __shared__ float tile[32][33];
  int n0 = blockIdx.x * 32;
  int k0 = blockIdx.y * 32;
  int tx = threadIdx.x & 31, ty = threadIdx.x >> 5;  // ty in [0,8)
  #pragma unroll
  for (int i = 0; i < 4; ++i)
    tile[ty + i * 8][tx] = U[(size_t)(k0 + ty + i * 8) * 4096 + n0 + tx];
  __syncthreads();
  int nrel = threadIdx.x >> 3;          // 0..31
  int kc = (threadIdx.x & 7) * 4;       // 0..28
  union { unsigned short u[4]; uint2 v8; } pk;
  #pragma unroll
  for (int i = 0; i < 4; ++i) pk.u[i] = f2bf(tile[kc + i][nrel]);
  *(uint2*)(Bt + (size_t)(n0 + nrel) * 2048 + k0 + kc) = pk.v8;
}

// GEMM + fused LSTM epilogue.
// Grid: 1024 flat blocks (16 p-tiles x 64 m-tiles after XCD swizzle),
// 512 threads (8 waves: wm in [0,2) x wn in [0,4)); per-wave 128x64 output.
// LDS (dynamic, 128 KiB): A slots [4][256][32]bf16 @0, B slots @64KiB.
// 64B rows, 16B segs XOR-swizzled by (row>>1)&3 (both-sides involution:
// pre-swizzled global src for global_load_lds, swizzled ds_read addr).
// B LDS p-row rl holds physical n = ((rl>>4)&3)*1024 + j0 + (rl>>6)*16 + (rl&15)
// so acc[mi][ni] = gate ni of column j0 + wn*16 + cc.
// Pipeline: prefetch tile t+2 while computing tile t; ONE s_waitcnt vmcnt(4)
// per K-tile (t+1's 4 loads forced complete, t+2's 4 stay in flight across
// the raw s_barriers). Slot overwritten 2 tiles (>=4 barriers) after last read.
__global__ __launch_bounds__(512, 2)
void lstm_gemm(const unsigned short* __restrict__ A, const unsigned short* __restrict__ Bt,
               const float* __restrict__ c0, float* __restrict__ out) {
  extern __shared__ char smem[];  // 131072 bytes
  const int tid = threadIdx.x;
  const int wave = tid >> 6, lane = tid & 63;
  const int q = lane >> 4, cc = lane & 15;
  const int wm = wave >> 2, wn = wave & 3;

  // T1: bijective XCD swizzle (nwg=1024 % 8 == 0). Consecutive swz ids within
  // an XCD chunk share the A-panel (by) across all 16 bx -> A reuse hits L2.
  const int bid = blockIdx.x;
  const int swz = (bid & 7) * 128 + (bid >> 3);
  const int m0 = (swz >> 4) * 256;
  const int j0 = (swz & 15) * 64;

  // Staging source offsets (bytes/lane) for the two 128-row units per operand.
  // Lane l covers LDS row u*128 + wave*16 + (l>>2), 16B seg (l&3); the seg is
  // pre-XOR'd with row bits 1-2 so the linear global_load_lds write lands the
  // swizzled layout (rule: both-sides-or-neither).
  const int srow = lane >> 2;
  const int sseg = (lane & 3) ^ ((lane >> 3) & 3);
  uint32_t aoff[2], boff[2];
  #pragma unroll
  for (int u = 0; u < 2; ++u) {
    int rl = u * 128 + wave * 16 + srow;     // LDS row 0..255
    aoff[u] = (((uint32_t)(m0 + rl) << 11) + (uint32_t)(sseg * 8)) * 2u;
    int n = (((rl >> 4) & 3) << 10) + j0 + ((rl >> 6) << 4) + (rl & 15);
    boff[u] = (((uint32_t)n << 11) + (uint32_t)(sseg * 8)) * 2u;
  }
  const char* Ab = (const char*)A;
  const char* Bb = (const char*)Bt;

  auto stageA = [&](int tt, int slot) {
    #pragma unroll
    for (int u = 0; u < 2; ++u) {
      uintptr_t l = (uintptr_t)(smem + slot * 16384 + u * 8192 + wave * 1024);
      __builtin_amdgcn_global_load_lds(
          (const __attribute__((address_space(1))) void*)(uintptr_t)(Ab + (aoff[u] + (uint32_t)tt * 64u)),
          (__attribute__((address_space(3))) void*)(uint32_t)l, 16, 0, 0);
    }
  };
  auto stageB = [&](int tt, int slot) {
    #pragma unroll
    for (int u = 0; u < 2; ++u) {
      uintptr_t l = (uintptr_t)(smem + 65536 + slot * 16384 + u * 8192 + wave * 1024);
      __builtin_amdgcn_global_load_lds(
          (const __attribute__((address_space(1))) void*)(uintptr_t)(Bb + (boff[u] + (uint32_t)tt * 64u)),
          (__attribute__((address_space(3))) void*)(uint32_t)l, 16, 0, 0);
    }
  };

  f32x4 acc[8][4];
  #pragma unroll
  for (int a = 0; a < 8; ++a)
    #pragma unroll
    for (int b = 0; b < 4; ++b)
      acc[a][b] = f32x4{0.f, 0.f, 0.f, 0.f};

  // Prologue: stage tiles 0 and 1 (8 loads/wave); force tile 0 landed,
  // keep tile 1's 4 in flight.
  stageA(0, 0); stageB(0, 0);
  stageA(1, 1); stageB(1, 1);
  asm volatile("s_waitcnt vmcnt(4)" ::: "memory");
  __builtin_amdgcn_s_barrier();

  // Frag-read base offsets (seg-swizzled by row bits 1-2, which come from cc).
  const uint32_t swzq = (uint32_t)((q ^ ((cc >> 1) & 3)) * 16);
  const uint32_t aRd = (uint32_t)((wm * 128 + cc) * 64) + swzq;
  const uint32_t bRd = 65536u + (uint32_t)((wn * 64 + cc) * 64) + swzq;

  for (int t = 0; t < NT; ++t) {
    const char* sbase = smem + (t & 3) * 16384;
    const int nslot = (t + 2) & 3;
    bf16x8 af[8], bf[4];
    // ---- phase 1: read A-lo + all B frags, issue next A stage, 16 MFMA ----
    #pragma unroll
    for (int mi = 0; mi < 4; ++mi) af[mi] = *(const bf16x8*)(sbase + aRd + mi * 1024);
    #pragma unroll
    for (int ni = 0; ni < 4; ++ni) bf[ni] = *(const bf16x8*)(sbase + bRd + ni * 1024);
    if (t < NT - 2) stageA(t + 2, nslot);
    __builtin_amdgcn_s_barrier();
    __builtin_amdgcn_s_setprio(1);
    #pragma unroll
    for (int mi = 0; mi < 4; ++mi)
      #pragma unroll
      for (int ni = 0; ni < 4; ++ni)
        acc[mi][ni] = __builtin_amdgcn_mfma_f32_16x16x32_bf16(af[mi], bf[ni], acc[mi][ni], 0, 0, 0);
    __builtin_amdgcn_s_setprio(0);
    __builtin_amdgcn_s_barrier();
    // ---- phase 2: read A-hi, issue next B stage, 16 MFMA ----
    #pragma unroll
    for (int mi = 4; mi < 8; ++mi) af[mi] = *(const bf16x8*)(sbase + aRd + mi * 1024);
    if (t < NT - 2) stageB(t + 2, nslot);
    __builtin_amdgcn_s_barrier();
    __builtin_amdgcn_s_setprio(1);
    #pragma unroll
    for (int mi = 4; mi < 8; ++mi)
      #pragma unroll
      for (int ni = 0; ni < 4; ++ni)
        acc[mi][ni] = __builtin_amdgcn_mfma_f32_16x16x32_bf16(af[mi], bf[ni], acc[mi][ni], 0, 0, 0);
    __builtin_amdgcn_s_setprio(0);
    // Counted wait: tile t+1's 4 loads (older) done; tile t+2's 4 stay in
    // flight. The following barrier makes that guarantee workgroup-wide.
    if (t < NT - 2) asm volatile("s_waitcnt vmcnt(4)" ::: "memory");
    else            asm volatile("s_waitcnt vmcnt(0)" ::: "memory");
    __builtin_amdgcn_s_barrier();
  }

  // Register-local fused epilogue: acc[mi][0..3] = i,f,g,o of (grow, gj).
  // C-layout: col = lane&15 (= cc), row = q*4 + r.
  const int gj = j0 + wn * 16 + cc;
  #pragma unroll
  for (int mi = 0; mi < 8; ++mi) {
    #pragma unroll
    for (int r = 0; r < 4; ++r) {
      int grow = m0 + wm * 128 + mi * 16 + q * 4 + r;
      float iv = fsig(acc[mi][0][r]);
      float fv = fsig(acc[mi][1][r]);
      float gv = ftanh_(acc[mi][2][r]);
      float ov = fsig(acc[mi][3][r]);
      float c0v = c0[(size_t)grow * DH + gj];
      float cv = fv * c0v + iv * gv;
      float hv = ov * ftanh_(cv);
      out[(size_t)grow * DH + gj] = hv;
      out[HC_ELEMS + (size_t)grow * DH + gj] = cv;
    }
  }
}

extern "C" void kernel_launch(void* const* d_in, const int* in_sizes, int n_in,
                              void* d_out, int out_size, void* d_ws, size_t ws_size,
                              hipStream_t stream) {
  const float* X  = (const float*)d_in[0];
  const float* h0 = (const float*)d_in[1];
  const float* c0 = (const float*)d_in[2];
  const float* U  = (const float*)d_in[3];
  const float* W  = (const float*)d_in[4];
  float* out = (float*)d_out;

  // ws layout: A_bf16 (16384x2048, 64MB) | Bt_bf16 (4096x2048, 16MB) = 80MB
  unsigned short* Abf = (unsigned short*)d_ws;
  unsigned short* Bt  = Abf + 33554432ull;

  static bool attr_set = false;
  if (!attr_set) {
    (void)hipFuncSetAttribute(reinterpret_cast<const void*>(lstm_gemm),
                              hipFuncAttributeMaxDynamicSharedMemorySize, 131072);
    attr_set = true;
  }

  cast_concat_A<<<16384, 256, 0, stream>>>(X, h0, Abf);
  cast_W<<<2048, 256, 0, stream>>>(W, Bt);
  transpose_U<<<dim3(128, 32), 256, 0, stream>>>(U, Bt);
  lstm_gemm<<<1024, 512, 131072, stream>>>(Abf, Bt, c0, out);
}

// Round 2
// 529.839 us; speedup vs baseline: 1.0113x; 1.0113x over previous
//
#include <hip/hip_runtime.h>
#include <hip/hip_bf16.h>
#include <stdint.h>

// LSTM cell: gates = [X|h0](16384x2048) @ Bt^T(2048x4096), fused epilogue.
// bf16 MFMA 16x16x32, 256x256 tile, 8 waves, BK=32, 4-deep LDS slots.
// R1 change: ONE barrier per K-tile (was 4). Slot hazard analysis allows it:
// gload(t+2) overwrites slot last read at tile t-2, and a single full barrier
// per tile separates them. Waves skew within the tile -> LDS pipe (768cyc)
// and matrix pipe (1242cyc) co-run instead of alternating.
// Gate-interleaved p-space so acc[mi][0..3] = gates i,f,g,o of ONE output
// column in the SAME lane -> epilogue is pure register math.

typedef __bf16 bf16x8 __attribute__((ext_vector_type(8)));
typedef float f32x4 __attribute__((ext_vector_type(4)));

#define B_ROWS 16384
#define KDIM 2048
#define DH 1024
#define HC_ELEMS 16777216ull  // 16384*1024
#define NT 64                 // K-tiles of BK=32

__device__ __forceinline__ unsigned short f2bf(float f) {
  unsigned u = __float_as_uint(f);
  u = (u + 0x7fffu + ((u >> 16) & 1u)) >> 16;  // RNE
  return (unsigned short)u;
}

__device__ __forceinline__ float fsig(float x) {
  return __builtin_amdgcn_rcpf(1.0f + __expf(-x));
}
__device__ __forceinline__ float ftanh_(float x) {
  return 2.0f * __builtin_amdgcn_rcpf(1.0f + __expf(-2.0f * x)) - 1.0f;
}

// A[m][k] = k<1024 ? X[m][k] : h0[m][k-1024], cast to bf16. 16 elems/thread
// (chunks of 16 never straddle the 1024 boundary).
__global__ void cast_concat_A(const float* __restrict__ X, const float* __restrict__ h0,
                              unsigned short* __restrict__ A) {
  size_t t = (size_t)blockIdx.x * 256 + threadIdx.x;
  size_t idx = t * 16;
  int m = (int)(idx >> 11);
  int k = (int)(idx & 2047);
  const float* src = (k < 1024) ? (X + (size_t)m * 1024 + k)
                                : (h0 + (size_t)m * 1024 + (k - 1024));
  float4 a = ((const float4*)src)[0];
  float4 b = ((const float4*)src)[1];
  float4 c = ((const float4*)src)[2];
  float4 d = ((const float4*)src)[3];
  union { unsigned short u[16]; uint4 v[2]; } pk;
  pk.u[0] = f2bf(a.x); pk.u[1] = f2bf(a.y); pk.u[2] = f2bf(a.z); pk.u[3] = f2bf(a.w);
  pk.u[4] = f2bf(b.x); pk.u[5] = f2bf(b.y); pk.u[6] = f2bf(b.z); pk.u[7] = f2bf(b.w);
  pk.u[8]  = f2bf(c.x); pk.u[9]  = f2bf(c.y); pk.u[10] = f2bf(c.z); pk.u[11] = f2bf(c.w);
  pk.u[12] = f2bf(d.x); pk.u[13] = f2bf(d.y); pk.u[14] = f2bf(d.z); pk.u[15] = f2bf(d.w);
  *(uint4*)(A + idx) = pk.v[0];
  *(uint4*)(A + idx + 8) = pk.v[1];
}

// Bt[n][1024+k'] = W[n][k'] (contiguous copy+cast). 16 elems/thread.
__global__ void cast_W(const float* __restrict__ W, unsigned short* __restrict__ Bt) {
  size_t t = (size_t)blockIdx.x * 256 + threadIdx.x;
  size_t idx = t * 16;  // over 4096*1024
  int n = (int)(idx >> 10);
  int k = (int)(idx & 1023);
  const float* src = W + (size_t)n * 1024 + k;
  float4 a = ((const float4*)src)[0];
  float4 b = ((const float4*)src)[1];
  float4 c = ((const float4*)src)[2];
  float4 d = ((const float4*)src)[3];
  union { unsigned short u[16]; uint4 v[2]; } pk;
  pk.u[0] = f2bf(a.x); pk.u[1] = f2bf(a.y); pk.u[2] = f2bf(a.z); pk.u[3] = f2bf(a.w);
  pk.u[4] = f2bf(b.x); pk.u[5] = f2bf(b.y); pk.u[6] = f2bf(b.z); pk.u[7] = f2bf(b.w);
  pk.u[8]  = f2bf(c.x); pk.u[9]  = f2bf(c.y); pk.u[10] = f2bf(c.z); pk.u[11] = f2bf(c.w);
  pk.u[12] = f2bf(d.x); pk.u[13] = f2bf(d.y); pk.u[14] = f2bf(d.z); pk.u[15] = f2bf(d.w);
  unsigned short* dst = Bt + (size_t)n * 2048 + 1024 + k;
  *(uint4*)(dst) = pk.v[0];
  *(uint4*)(dst + 8) = pk.v[1];
}

// Bt[n][k] = U[k][n] for k<1024. 32x32 LDS tile transpose, fp32->bf16.
__global__ void transpose_U(const float* __restrict__ U, unsigned short* __restrict__ Bt) {
  __shared__ float tile[32][33];
  int n0 = blockIdx.x * 32;
  int k0 = blockIdx.y * 32;
  int tx = threadIdx.x & 31, ty = threadIdx.x >> 5;  // ty in [0,8)
  #pragma unroll
  for (int i = 0; i < 4; ++i)
    tile[ty + i * 8][tx] = U[(size_t)(k0 + ty + i * 8) * 4096 + n0 + tx];
  __syncthreads();
  int nrel = threadIdx.x >> 3;          // 0..31
  int kc = (threadIdx.x & 7) * 4;       // 0..28
  union { unsigned short u[4]; uint2 v8; } pk;
  #pragma unroll
  for (int i = 0; i < 4; ++i) pk.u[i] = f2bf(tile[kc + i][nrel]);
  *(uint2*)(Bt + (size_t)(n0 + nrel) * 2048 + k0 + kc) = pk.v8;
}

// GEMM + fused LSTM epilogue.
// Grid: 1024 flat blocks (16 p-tiles x 64 m-tiles after XCD swizzle),
// 512 threads (8 waves: wm in [0,2) x wn in [0,4)); per-wave 128x64 output.
// LDS (dynamic, 128 KiB): A slots [4][256][32]bf16 @0, B slots @64KiB.
// 64B rows, 16B segs XOR-swizzled by (row>>1)&3 (both-sides involution:
// pre-swizzled global src for global_load_lds, swizzled ds_read addr).
// B LDS p-row rl holds physical n = ((rl>>4)&3)*1024 + j0 + (rl>>6)*16 + (rl&15)
// so acc[mi][ni] = gate ni of column j0 + wn*16 + cc.
// Pipeline per tile t: issue gloads(t+2) -> 12 ds_read_b128 -> 32 MFMA
// (setprio-wrapped) -> vmcnt(4) -> ONE s_barrier. t+2's 4 loads stay in
// flight across the barrier; t+1's are forced complete.
__global__ __launch_bounds__(512, 2)
void lstm_gemm(const unsigned short* __restrict__ A, const unsigned short* __restrict__ Bt,
               const float* __restrict__ c0, float* __restrict__ out) {
  extern __shared__ char smem[];  // 131072 bytes
  const int tid = threadIdx.x;
  const int wave = tid >> 6, lane = tid & 63;
  const int q = lane >> 4, cc = lane & 15;
  const int wm = wave >> 2, wn = wave & 3;

  // T1: bijective XCD swizzle (nwg=1024 % 8 == 0).
  const int bid = blockIdx.x;
  const int swz = (bid & 7) * 128 + (bid >> 3);
  const int m0 = (swz >> 4) * 256;
  const int j0 = (swz & 15) * 64;

  // Staging source offsets (bytes/lane): lane l covers LDS row
  // u*128 + wave*16 + (l>>2), 16B seg (l&3) pre-XOR'd with row bits 1-2.
  const int srow = lane >> 2;
  const int sseg = (lane & 3) ^ ((lane >> 3) & 3);
  uint32_t aoff[2], boff[2];
  #pragma unroll
  for (int u = 0; u < 2; ++u) {
    int rl = u * 128 + wave * 16 + srow;     // LDS row 0..255
    aoff[u] = (((uint32_t)(m0 + rl) << 11) + (uint32_t)(sseg * 8)) * 2u;
    int n = (((rl >> 4) & 3) << 10) + j0 + ((rl >> 6) << 4) + (rl & 15);
    boff[u] = (((uint32_t)n << 11) + (uint32_t)(sseg * 8)) * 2u;
  }
  const char* Ab = (const char*)A;
  const char* Bb = (const char*)Bt;

  auto stageA = [&](int tt, int slot) {
    #pragma unroll
    for (int u = 0; u < 2; ++u) {
      uintptr_t l = (uintptr_t)(smem + slot * 16384 + u * 8192 + wave * 1024);
      __builtin_amdgcn_global_load_lds(
          (const __attribute__((address_space(1))) void*)(uintptr_t)(Ab + (aoff[u] + (uint32_t)tt * 64u)),
          (__attribute__((address_space(3))) void*)(uint32_t)l, 16, 0, 0);
    }
  };
  auto stageB = [&](int tt, int slot) {
    #pragma unroll
    for (int u = 0; u < 2; ++u) {
      uintptr_t l = (uintptr_t)(smem + 65536 + slot * 16384 + u * 8192 + wave * 1024);
      __builtin_amdgcn_global_load_lds(
          (const __attribute__((address_space(1))) void*)(uintptr_t)(Bb + (boff[u] + (uint32_t)tt * 64u)),
          (__attribute__((address_space(3))) void*)(uint32_t)l, 16, 0, 0);
    }
  };

  f32x4 acc[8][4];
  #pragma unroll
  for (int a = 0; a < 8; ++a)
    #pragma unroll
    for (int b = 0; b < 4; ++b)
      acc[a][b] = f32x4{0.f, 0.f, 0.f, 0.f};

  // Prologue: stage tiles 0 and 1; force tile 0 landed, keep tile 1 in flight.
  stageA(0, 0); stageB(0, 0);
  stageA(1, 1); stageB(1, 1);
  asm volatile("s_waitcnt vmcnt(4)" ::: "memory");
  __builtin_amdgcn_s_barrier();

  // Frag-read base offsets (seg-swizzled by row bits 1-2, which come from cc).
  const uint32_t swzq = (uint32_t)((q ^ ((cc >> 1) & 3)) * 16);
  const uint32_t aRd = (uint32_t)((wm * 128 + cc) * 64) + swzq;
  const uint32_t bRd = 65536u + (uint32_t)((wn * 64 + cc) * 64) + swzq;

  for (int t = 0; t < NT; ++t) {
    const char* sbase = smem + (t & 3) * 16384;
    // Issue next prefetch first: independent, goes to HBM earliest.
    if (t < NT - 2) {
      const int nslot = (t + 2) & 3;
      stageA(t + 2, nslot);
      stageB(t + 2, nslot);
    }
    bf16x8 af[8], bf[4];
    #pragma unroll
    for (int mi = 0; mi < 8; ++mi) af[mi] = *(const bf16x8*)(sbase + aRd + mi * 1024);
    #pragma unroll
    for (int ni = 0; ni < 4; ++ni) bf[ni] = *(const bf16x8*)(sbase + bRd + ni * 1024);
    __builtin_amdgcn_s_setprio(1);
    #pragma unroll
    for (int mi = 0; mi < 8; ++mi)
      #pragma unroll
      for (int ni = 0; ni < 4; ++ni)
        acc[mi][ni] = __builtin_amdgcn_mfma_f32_16x16x32_bf16(af[mi], bf[ni], acc[mi][ni], 0, 0, 0);
    __builtin_amdgcn_s_setprio(0);
    // Counted wait: tile t+1's 4 loads (older) done; tile t+2's 4 stay in
    // flight. The barrier publishes slot t+1 workgroup-wide and bounds the
    // wave skew to one tile (slot-overwrite safety needs just one barrier).
    if (t < NT - 2)      asm volatile("s_waitcnt vmcnt(4)" ::: "memory");
    else if (t == NT - 2) asm volatile("s_waitcnt vmcnt(0)" ::: "memory");
    if (t < NT - 1) __builtin_amdgcn_s_barrier();
  }

  // Register-local fused epilogue: acc[mi][0..3] = i,f,g,o of (grow, gj).
  // C-layout: col = lane&15 (= cc), row = q*4 + r.
  const int gj = j0 + wn * 16 + cc;
  #pragma unroll
  for (int mi = 0; mi < 8; ++mi) {
    #pragma unroll
    for (int r = 0; r < 4; ++r) {
      int grow = m0 + wm * 128 + mi * 16 + q * 4 + r;
      float iv = fsig(acc[mi][0][r]);
      float fv = fsig(acc[mi][1][r]);
      float gv = ftanh_(acc[mi][2][r]);
      float ov = fsig(acc[mi][3][r]);
      float c0v = c0[(size_t)grow * DH + gj];
      float cv = fv * c0v + iv * gv;
      float hv = ov * ftanh_(cv);
      out[(size_t)grow * DH + gj] = hv;
      out[HC_ELEMS + (size_t)grow * DH + gj] = cv;
    }
  }
}

extern "C" void kernel_launch(void* const* d_in, const int* in_sizes, int n_in,
                              void* d_out, int out_size, void* d_ws, size_t ws_size,
                              hipStream_t stream) {
  const float* X  = (const float*)d_in[0];
  const float* h0 = (const float*)d_in[1];
  const float* c0 = (const float*)d_in[2];
  const float* U  = (const float*)d_in[3];
  const float* W  = (const float*)d_in[4];
  float* out = (float*)d_out;

  // ws layout: A_bf16 (16384x2048, 64MB) | Bt_bf16 (4096x2048, 16MB) = 80MB
  unsigned short* Abf = (unsigned short*)d_ws;
  unsigned short* Bt  = Abf + 33554432ull;

  static bool attr_set = false;
  if (!attr_set) {
    (void)hipFuncSetAttribute(reinterpret_cast<const void*>(lstm_gemm),
                              hipFuncAttributeMaxDynamicSharedMemorySize, 131072);
    attr_set = true;
  }

  cast_concat_A<<<8192, 256, 0, stream>>>(X, h0, Abf);
  cast_W<<<1024, 256, 0, stream>>>(W, Bt);
  transpose_U<<<dim3(128, 32), 256, 0, stream>>>(U, Bt);
  lstm_gemm<<<1024, 512, 131072, stream>>>(Abf, Bt, c0, out);
}